// Round 7
// baseline (557.103 us; speedup 1.0000x reference)
//
#include <hip/hip_runtime.h>

typedef __attribute__((ext_vector_type(8))) __bf16 bf16x8;
typedef __attribute__((ext_vector_type(8))) unsigned short ushort8;
typedef __attribute__((ext_vector_type(4))) float f32x4;
typedef __attribute__((ext_vector_type(2))) unsigned long long u64x2;

#define DEVINL __device__ __forceinline__
#define RLX __ATOMIC_RELAXED
#define AGT __HIP_MEMORY_SCOPE_AGENT

constexpr int B_C    = 512;
constexpr int DIMS_C = 784;
constexpr int T_C    = 55;      // K1*N time steps
constexpr int I0_C   = 789;     // DIMS + N
constexpr int KP_C   = 800;     // padded K for gemm1 (25 * 32)
constexpr int H_C    = 512;
constexpr int G4_C   = 2048;    // 4*H
constexpr int M1_C   = 28160;   // T_C * B_C, rows ordered r = t*512 + b

// ---- workspace layout (bytes, all 256-aligned) ----
constexpr size_t OFF_A    = 0;                                   // bf16 [M1][KP]
constexpr size_t SZ_A     = (size_t)M1_C * KP_C * 2;
constexpr size_t OFF_W1T  = OFF_A + SZ_A;                        // bf16 [2048][KP]
constexpr size_t SZ_W1T   = (size_t)G4_C * KP_C * 2;
constexpr size_t OFF_U1T  = OFF_W1T + SZ_W1T;                    // bf16 [2048][512]
constexpr size_t SZ_U1T   = (size_t)G4_C * H_C * 2;
constexpr size_t OFF_XW1  = OFF_U1T + SZ_U1T;                    // fp16 [M1][2048]
constexpr size_t SZ_XW1   = (size_t)M1_C * G4_C * 2;
constexpr size_t OFF_H    = OFF_XW1 + SZ_XW1;                    // bf16 [2][512][512]
constexpr size_t SZ_H     = (size_t)2 * B_C * H_C * 2;
constexpr size_t OFF_XMID = OFF_H + SZ_H;                        // f32 [M1][512]
constexpr size_t SZ_XMID  = (size_t)M1_C * H_C * 4;
constexpr size_t OFF_XW2  = OFF_XMID + SZ_XMID;                  // f32 [M1][20]
constexpr size_t SZ_XW2   = (size_t)M1_C * 20 * 4;
constexpr size_t OFF_W2T  = OFF_XW2 + SZ_XW2;                    // f32 [20][512]
constexpr size_t SZ_W2T   = (size_t)20 * H_C * 4;
constexpr size_t OFF_CNT  = OFF_W2T + SZ_W2T;                    // u32 flags, one per 64B line

// ---- helpers ----
DEVINL unsigned short f2bf(float f) {
  unsigned u = __builtin_bit_cast(unsigned, f);
  u += 0x7fffu + ((u >> 16) & 1u);          // RNE
  return (unsigned short)(u >> 16);
}
DEVINL float sigm(float x) {
  return __builtin_amdgcn_rcpf(1.f + __builtin_amdgcn_exp2f(-1.4426950408889634f * x));
}
DEVINL float tanh_(float x) {
  return 2.f * __builtin_amdgcn_rcpf(1.f + __builtin_amdgcn_exp2f(-2.8853900817779268f * x)) - 1.f;
}
DEVINL void gl_lds16(const void* g, void* l) {
  __builtin_amdgcn_global_load_lds((const __attribute__((address_space(1))) void*)g,
                                   (__attribute__((address_space(3))) void*)l, 16, 0, 0);
}
DEVINL void gl_lds16_coh(const void* g, void* l) {   // SC0|SC1: bypass non-coherent L2, read at IC
  __builtin_amdgcn_global_load_lds((const __attribute__((address_space(1))) void*)g,
                                   (__attribute__((address_space(3))) void*)l, 16, 0, 17);
}

// ================= pack kernels =================

__global__ void pack_a(const float* __restrict__ img, const float* __restrict__ lbl,
                       unsigned short* __restrict__ A) {
  int gid = blockIdx.x * blockDim.x + threadIdx.x;
  constexpr int CPR = KP_C / 8;                       // 100 chunks per row
  if (gid >= M1_C * CPR) return;
  int r  = gid / CPR;
  int cc = gid - r * CPR;
  int t = r >> 9, b = r & 511;
  int k1 = t / 5, n = t - k1 * 5;
  int c0 = cc * 8;
  ushort8 v;
  if (c0 + 8 <= DIMS_C) {
    const float* p = img + ((size_t)((b * 11 + k1) * 5 + n)) * DIMS_C + c0;
    f32x4 x0 = *(const f32x4*)(p);
    f32x4 x1 = *(const f32x4*)(p + 4);
#pragma unroll
    for (int j = 0; j < 4; ++j) { v[j] = f2bf(x0[j]); v[4 + j] = f2bf(x1[j]); }
  } else {
#pragma unroll
    for (int j = 0; j < 8; ++j) {
      int c = c0 + j;
      float x = 0.f;
      if (c < DIMS_C) x = img[((size_t)((b * 11 + k1) * 5 + n)) * DIMS_C + c];
      else if (c < I0_C && k1 < 10) x = lbl[((size_t)((b * 11 + k1) * 5 + n)) * 5 + (c - DIMS_C)];
      v[j] = f2bf(x);
    }
  }
  *(ushort8*)(A + (size_t)r * KP_C + c0) = v;
}

__global__ void pack_w1t(const float* __restrict__ W1, unsigned short* __restrict__ W1T) {
  int gid = blockIdx.x * blockDim.x + threadIdx.x;
  if (gid >= G4_C * KP_C) return;
  int col = gid / KP_C, k = gid - col * KP_C;
  float x = (k < I0_C) ? W1[(size_t)k * G4_C + col] : 0.f;
  W1T[(size_t)col * KP_C + k] = f2bf(x);
}

__global__ void pack_u1t(const float* __restrict__ U1, unsigned short* __restrict__ U1T) {
  int gid = blockIdx.x * blockDim.x + threadIdx.x;
  if (gid >= G4_C * H_C) return;
  int col = gid / H_C, k = gid - col * H_C;
  U1T[(size_t)col * H_C + k] = f2bf(U1[(size_t)k * G4_C + col]);
}

__global__ void pack_w2t(const float* __restrict__ W2, float* __restrict__ W2T) {
  int gid = blockIdx.x * blockDim.x + threadIdx.x;
  if (gid >= 20 * H_C) return;
  int col = gid / H_C, k = gid - col * H_C;
  W2T[(size_t)col * H_C + k] = W2[(size_t)k * 20 + col];
}

// ================= gemm1: xw1 = A @ W1 + b1  (bf16 MFMA, 2-phase + XCD swizzle) =====
// grid = 3520 linear; chunked-bijective XCD swizzle (3520 % 8 == 0): blocks on one
// XCD cover a contiguous (by,bx) range -> A-tile reused 16x in-XCD, Bt (3.2MB) L2-resident.
__launch_bounds__(256, 2)
__global__ void gemm1(const unsigned short* __restrict__ A,
                      const unsigned short* __restrict__ Bt,
                      const float* __restrict__ bias,
                      _Float16* __restrict__ C)
{
  __shared__ unsigned short sA[2][128 * 32];
  __shared__ unsigned short sB[2][128 * 32];
  const int tid = threadIdx.x;
  const int w = tid >> 6, l = tid & 63;
  const int lo = l & 15, hi = l >> 4;
  const int wm = w >> 1, wn = w & 1;
  const int id = blockIdx.x;
  const int swz = (id & 7) * 440 + (id >> 3);   // XCD chunked, bijective
  const int by = swz >> 4;                      // 0..219  (M tiles)
  const int bx = swz & 15;                      // 0..15   (N tiles)

  const unsigned short* aSrc[2];
  const unsigned short* bSrc[2];
#pragma unroll
  for (int q = 0; q < 2; ++q) {
    int row = w * 32 + q * 16 + (l >> 2);
    int ch = l & 3;
    int sw = (row >> 1) & 3;
    aSrc[q] = A  + (size_t)(by * 128 + row) * KP_C + (ch ^ sw) * 8;
    bSrc[q] = Bt + (size_t)(bx * 128 + row) * KP_C + (ch ^ sw) * 8;
  }
  int aOff[4], bOff[4];
#pragma unroll
  for (int i = 0; i < 4; ++i) {
    int rA = wm * 64 + i * 16 + lo;
    aOff[i] = rA * 32 + ((hi ^ ((rA >> 1) & 3)) * 8);
    int rB = wn * 64 + i * 16 + lo;
    bOff[i] = rB * 32 + ((hi ^ ((rB >> 1) & 3)) * 8);
  }

  f32x4 acc[4][4];
#pragma unroll
  for (int i = 0; i < 4; ++i)
#pragma unroll
    for (int j = 0; j < 4; ++j) acc[i][j] = (f32x4){0.f, 0.f, 0.f, 0.f};

#define G1_STAGE(buf, ks)                                                  \
  {                                                                        \
    _Pragma("unroll")                                                      \
    for (int q = 0; q < 2; ++q) {                                          \
      gl_lds16(aSrc[q] + (ks) * 32, &sA[buf][w * 1024 + q * 512]);         \
      gl_lds16(bSrc[q] + (ks) * 32, &sB[buf][w * 1024 + q * 512]);         \
    }                                                                      \
  }

  G1_STAGE(0, 0);
  asm volatile("s_waitcnt vmcnt(0)" ::: "memory");
  __syncthreads();

  int cur = 0;
#pragma unroll 1
  for (int ks = 0; ks < KP_C / 32; ++ks) {
    if (ks < KP_C / 32 - 1) G1_STAGE(cur ^ 1, ks + 1);
    bf16x8 af[4], bfr[4];
#pragma unroll
    for (int i = 0; i < 4; ++i) {
      af[i]  = *(const bf16x8*)(&sA[cur][0] + aOff[i]);
      bfr[i] = *(const bf16x8*)(&sB[cur][0] + bOff[i]);
    }
#pragma unroll
    for (int mi = 0; mi < 4; ++mi)
#pragma unroll
      for (int ni = 0; ni < 4; ++ni)
        acc[mi][ni] = __builtin_amdgcn_mfma_f32_16x16x32_bf16(af[mi], bfr[ni], acc[mi][ni], 0, 0, 0);
    asm volatile("s_waitcnt vmcnt(0)" ::: "memory");
    __syncthreads();
    cur ^= 1;
  }
#undef G1_STAGE

  const size_t crow0 = (size_t)by * 128 + wm * 64;
  const int ccol0 = bx * 128 + wn * 64;
#pragma unroll
  for (int ni = 0; ni < 4; ++ni) {
    int col = ccol0 + ni * 16 + lo;
    float bv = bias[col];
#pragma unroll
    for (int mi = 0; mi < 4; ++mi) {
#pragma unroll
      for (int j = 0; j < 4; ++j) {
        size_t row = crow0 + mi * 16 + hi * 4 + j;
        C[row * G4_C + col] = (_Float16)(acc[mi][ni][j] + bv);
      }
    }
  }
}

// ================= lstm1: persistent recurrence, gate-in-lane (no sG) =============
// 256 blocks = 16 batch-groups (32 rows) x 16 unit-groups (32 units), 1 block/CU.
// Wave w owns units ub+w*8..+7 x ALL 4 gates: MFMA col c = gt*8+q. The 4 gates of
// a cell live in lanes q, q+8 (frag pair) -> one shfl_xor(8) replaces the sG LDS
// exchange + its barrier. 2 barriers/step. h via relaxed agent (sc1/IC) ops;
// per-wave 16-line flag poll; stage via coherent global_load_lds, pre-swizzled src.
__launch_bounds__(256, 1)
__global__ void lstm1(const _Float16* __restrict__ xw,        // [M1][2048]
                      const unsigned short* __restrict__ U1T, // [2048 cols][512 k] bf16
                      unsigned short* __restrict__ hbuf,      // [2][512][512] bf16
                      float* __restrict__ xmid,               // [M1][512]
                      unsigned int* __restrict__ cnt)         // flag (bg,cg) at [(bg*16+cg)*16]
{
  __shared__ unsigned short sH[32 * 512];   // linear 32KB; [row][chunk c] = global chunk c^(row&7)

  const int tid = threadIdx.x;
  const int w = tid >> 6;                   // wave = unit octet
  const int l = tid & 63;
  const int lo = l & 15, hi = l >> 4;
  const int q = lo & 7;                     // unit within octet
  const int gsel = lo >> 3;                 // 0: frag gates (i,g); 1: (f,o)
  const int bg = blockIdx.x >> 4;
  const int cg = blockIdx.x & 15;
  const int brow0 = bg * 32;
  const int ub = cg * 32;
  const int unit = ub + w * 8 + q;          // global unit this lane owns

  // U1 B-fragments: bu[nf][kk], col = (nf*2+gsel)*512 + unit, k = kk*32 + hi*8 + i
  bf16x8 bu[2][16];
#pragma unroll
  for (int nf = 0; nf < 2; ++nf) {
    const unsigned short* src = U1T + ((size_t)((nf * 2 + gsel) * H_C + unit)) * H_C + hi * 8;
#pragma unroll
    for (int kk = 0; kk < 16; ++kk)
      bu[nf][kk] = *(const bf16x8*)(src + kk * 32);
  }

  // A-frag addressing (pre-swizzled stage): rows lo and 16+lo; (16+lo)&7 == lo&7
  const int s0 = lo & 7;
  const int aO0 = lo * 1024;
  const int aO1 = aO0 + 16 * 1024;

  float c_st[8];                            // cells: [mf*4+j], rows mf*16+hi*4+j
#pragma unroll
  for (int i = 0; i < 8; ++i) c_st[i] = 0.f;

  // xw: xwv[nf][mf][j] = xw[(t*512+brow0+mf*16+hi*4+j)*2048 + (nf*2+gsel)*512 + unit]
  const _Float16* xb = xw + (size_t)(brow0 + hi * 4) * G4_C + gsel * H_C + unit;
  float xwv[2][2][4];
#pragma unroll
  for (int nf = 0; nf < 2; ++nf)
#pragma unroll
    for (int mf = 0; mf < 2; ++mf)
#pragma unroll
      for (int j = 0; j < 4; ++j)
        xwv[nf][mf][j] = (float)xb[(size_t)(mf * 16 + j) * G4_C + nf * 1024];

#pragma unroll 1
  for (int t = 0; t < T_C; ++t) {
    f32x4 acc[2][2];
#pragma unroll
    for (int mf = 0; mf < 2; ++mf)
#pragma unroll
      for (int nf = 0; nf < 2; ++nf) acc[mf][nf] = (f32x4){0.f, 0.f, 0.f, 0.f};

    if (t > 0) {
      // ---- per-wave poll: 16 flags, each in its own 64B line (clean vmcnt)
      {
        const unsigned* fp = cnt + (size_t)(bg * 16 + (l & 15)) * 16;
        unsigned target = (unsigned)t;
        while (true) {
          unsigned v = __hip_atomic_load(fp, RLX, AGT);
          if (__all(v >= target)) break;
          __builtin_amdgcn_s_sleep(1);
        }
      }
      asm volatile("" ::: "memory");

      // ---- stage h(t): wave w stages rows w*8..w*8+7, source pre-swizzled (l^p)
      const unsigned short* hsrc = hbuf + (size_t)(t & 1) * (B_C * H_C);
#pragma unroll
      for (int p = 0; p < 8; ++p) {
        int row = w * 8 + p;                               // row&7 == p
        gl_lds16_coh(hsrc + (size_t)(brow0 + row) * H_C + ((l ^ p) * 8),
                     sH + row * 512);
      }
      asm volatile("s_waitcnt vmcnt(0)" ::: "memory");
      __syncthreads();

      // ---- z = h @ U1 (cols: this wave's 8 units x 4 gates)
#pragma unroll
      for (int kk = 0; kk < 16; ++kk) {
        int off = (((kk * 4 + hi) ^ s0) << 4);
        bf16x8 a0 = *(const bf16x8*)((const char*)sH + aO0 + off);
        bf16x8 a1 = *(const bf16x8*)((const char*)sH + aO1 + off);
        acc[0][0] = __builtin_amdgcn_mfma_f32_16x16x32_bf16(a0, bu[0][kk], acc[0][0], 0, 0, 0);
        acc[0][1] = __builtin_amdgcn_mfma_f32_16x16x32_bf16(a0, bu[1][kk], acc[0][1], 0, 0, 0);
        acc[1][0] = __builtin_amdgcn_mfma_f32_16x16x32_bf16(a1, bu[0][kk], acc[1][0], 0, 0, 0);
        acc[1][1] = __builtin_amdgcn_mfma_f32_16x16x32_bf16(a1, bu[1][kk], acc[1][1], 0, 0, 0);
      }
    }

    // ---- in-wave gate exchange + state update (no LDS, no barrier)
    float hnew[8];
#pragma unroll
    for (int mf = 0; mf < 2; ++mf)
#pragma unroll
      for (int j = 0; j < 4; ++j) {
        float za = acc[mf][0][j] + xwv[0][mf][j];   // gate gsel   (i or f)
        float zb = acc[mf][1][j] + xwv[1][mf][j];   // gate 2+gsel (g or o)
        float zap = __shfl_xor(za, 8);
        float zbp = __shfl_xor(zb, 8);
        float zi = gsel ? zap : za;
        float zf = gsel ? za : zap;
        float zg = gsel ? zbp : zb;
        float zo = gsel ? zb : zbp;
        float iv = sigm(zi), fv = sigm(zf), gv = tanh_(zg), ov = sigm(zo);
        int ci = mf * 4 + j;
        float cv = fv * c_st[ci] + iv * gv;
        c_st[ci] = cv;
        hnew[ci] = ov * tanh_(cv);
      }

    if (t < T_C - 1) {
      // ---- h(t+1) coherent packed-u32 stores (lanes q even, lo<8)
      unsigned short* hd = hbuf + (size_t)((t & 1) ^ 1) * (B_C * H_C);
#pragma unroll
      for (int mf = 0; mf < 2; ++mf)
#pragma unroll
        for (int j = 0; j < 4; ++j) {
          int ci = mf * 4 + j;
          float other = __shfl_xor(hnew[ci], 1);
          if (lo < 8 && (q & 1) == 0) {
            int row = mf * 16 + hi * 4 + j;
            unsigned val = (unsigned)f2bf(hnew[ci]) | ((unsigned)f2bf(other) << 16);
            __hip_atomic_store((unsigned*)(hd + (size_t)(brow0 + row) * H_C + unit), val,
                               RLX, AGT);
          }
        }

      // ---- xmid (regular stores) + xw(t+1) prefetch BEFORE the drain barrier
#pragma unroll
      for (int mf = 0; mf < 2; ++mf)
#pragma unroll
        for (int j = 0; j < 4; ++j)
          if (lo < 8) {
            int row = mf * 16 + hi * 4 + j;
            xmid[((size_t)t * B_C + brow0 + row) * H_C + unit] = hnew[mf * 4 + j];
          }
      const _Float16* xp = xb + (size_t)(t + 1) * B_C * G4_C;
#pragma unroll
      for (int nf = 0; nf < 2; ++nf)
#pragma unroll
        for (int mf = 0; mf < 2; ++mf)
#pragma unroll
          for (int j = 0; j < 4; ++j)
            xwv[nf][mf][j] = (float)xp[(size_t)(mf * 16 + j) * G4_C + nf * 1024];

      // drain everything (h stores at coherence point), then signal; poll stays clean
      asm volatile("s_waitcnt vmcnt(0)" ::: "memory");
      __syncthreads();
      if (tid == 0)
        __hip_atomic_store(&cnt[(size_t)(bg * 16 + cg) * 16], (unsigned)(t + 1), RLX, AGT);
    } else {
#pragma unroll
      for (int mf = 0; mf < 2; ++mf)
#pragma unroll
        for (int j = 0; j < 4; ++j)
          if (lo < 8) {
            int row = mf * 16 + hi * 4 + j;
            xmid[((size_t)t * B_C + brow0 + row) * H_C + unit] = hnew[mf * 4 + j];
          }
    }
  }
}

// ================= gemm2: xw2 = x_mid @ W2 + b2 (fp32, 1 thread/row) =================
__global__ void gemm2(const float* __restrict__ X,    // [M1][512]
                      const float* __restrict__ W2T,  // [20][512]
                      const float* __restrict__ b2,   // [20]
                      float* __restrict__ XW2)        // [M1][20]
{
  int r = blockIdx.x * blockDim.x + threadIdx.x;
  if (r >= M1_C) return;
  float acc[20];
#pragma unroll
  for (int j = 0; j < 20; ++j) acc[j] = b2[j];
  const float* xr = X + (size_t)r * H_C;
  for (int k = 0; k < H_C; k += 4) {
    f32x4 xv = *(const f32x4*)(xr + k);
#pragma unroll
    for (int j = 0; j < 20; ++j) {
      f32x4 wv = *(const f32x4*)(W2T + (size_t)j * H_C + k);
      acc[j] += xv[0]*wv[0] + xv[1]*wv[1] + xv[2]*wv[2] + xv[3]*wv[3];
    }
  }
  float* op = XW2 + (size_t)r * 20;
#pragma unroll
  for (int j = 0; j < 20; ++j) op[j] = acc[j];
}

// ================= lstm2: tiny recurrence, fp32 =================
__global__ void lstm2(const float* __restrict__ XW2,  // [M1][20]
                      const float* __restrict__ U2,   // [5][20]
                      float* __restrict__ out)        // [512][11][5][5]
{
  int b = blockIdx.x * blockDim.x + threadIdx.x;
  if (b >= B_C) return;
  float u2[5][20];
#pragma unroll
  for (int k = 0; k < 5; ++k)
#pragma unroll
    for (int j = 0; j < 20; ++j) u2[k][j] = U2[k * 20 + j];
  float h[5] = {0, 0, 0, 0, 0}, c[5] = {0, 0, 0, 0, 0};
  for (int t = 0; t < T_C; ++t) {
    const float* xr = XW2 + ((size_t)t * B_C + b) * 20;
    float z[20];
#pragma unroll
    for (int j = 0; j < 20; ++j) z[j] = xr[j];
#pragma unroll
    for (int k = 0; k < 5; ++k) {
      float hk = h[k];
#pragma unroll
      for (int j = 0; j < 20; ++j) z[j] += hk * u2[k][j];
    }
#pragma unroll
    for (int n = 0; n < 5; ++n) {
      float iv = sigm(z[n]), fv = sigm(z[5 + n]), gv = tanh_(z[10 + n]), ov = sigm(z[15 + n]);
      c[n] = fv * c[n] + iv * gv;
      h[n] = ov * tanh_(c[n]);
    }
    int k1 = t / 5, nn = t - k1 * 5;
    float* op = out + (((size_t)b * 11 + k1) * 5 + nn) * 5;
#pragma unroll
    for (int j = 0; j < 5; ++j) op[j] = h[j];
  }
}

// ================= launch =================
extern "C" void kernel_launch(void* const* d_in, const int* in_sizes, int n_in,
                              void* d_out, int out_size, void* d_ws, size_t ws_size,
                              hipStream_t stream) {
  (void)in_sizes; (void)n_in; (void)out_size; (void)ws_size;
  const float* img = (const float*)d_in[0];
  const float* lbl = (const float*)d_in[1];
  const float* W1  = (const float*)d_in[2];
  const float* U1  = (const float*)d_in[3];
  const float* b1  = (const float*)d_in[4];
  const float* W2  = (const float*)d_in[5];
  const float* U2  = (const float*)d_in[6];
  const float* b2  = (const float*)d_in[7];

  char* ws = (char*)d_ws;
  unsigned short* A    = (unsigned short*)(ws + OFF_A);
  unsigned short* W1T  = (unsigned short*)(ws + OFF_W1T);
  unsigned short* U1T  = (unsigned short*)(ws + OFF_U1T);
  _Float16*       XW1  = (_Float16*)      (ws + OFF_XW1);
  unsigned short* HB   = (unsigned short*)(ws + OFF_H);
  float*          XMID = (float*)         (ws + OFF_XMID);
  float*          XW2  = (float*)         (ws + OFF_XW2);
  float*          W2T  = (float*)         (ws + OFF_W2T);
  unsigned int*   CNT  = (unsigned int*)  (ws + OFF_CNT);

  hipMemsetAsync(CNT, 0, 256 * 64, stream);               // 256 flags, one per 64B line

  pack_a  <<<(M1_C * (KP_C / 8)) / 256, 256, 0, stream>>>(img, lbl, A);
  pack_w1t<<<(G4_C * KP_C) / 256,      256, 0, stream>>>(W1, W1T);
  pack_u1t<<<(G4_C * H_C) / 256,       256, 0, stream>>>(U1, U1T);
  pack_w2t<<<(20 * H_C + 255) / 256,   256, 0, stream>>>(W2, W2T);

  gemm1<<<3520, 256, 0, stream>>>(A, W1T, b1, XW1);
  lstm1<<<256, 256, 0, stream>>>(XW1, U1T, HB, XMID, CNT);
  gemm2<<<(M1_C + 255) / 256, 256, 0, stream>>>(XMID, W2T, b2, XW2);
  lstm2<<<8, 64, 0, stream>>>(XW2, U2, (float*)d_out);
}

// Round 8
// 458.238 us; speedup vs baseline: 1.2158x; 1.2158x over previous
//
#include <hip/hip_runtime.h>

typedef __attribute__((ext_vector_type(8))) __bf16 bf16x8;
typedef __attribute__((ext_vector_type(8))) unsigned short ushort8;
typedef __attribute__((ext_vector_type(4))) float f32x4;
typedef __attribute__((ext_vector_type(2))) unsigned long long u64x2;

#define DEVINL __device__ __forceinline__
#define RLX __ATOMIC_RELAXED
#define AGT __HIP_MEMORY_SCOPE_AGENT

constexpr int B_C    = 512;
constexpr int DIMS_C = 784;
constexpr int T_C    = 55;      // K1*N time steps
constexpr int I0_C   = 789;     // DIMS + N
constexpr int KP_C   = 800;     // padded K for gemm1 (25 * 32)
constexpr int H_C    = 512;
constexpr int G4_C   = 2048;    // 4*H
constexpr int M1_C   = 28160;   // T_C * B_C, rows ordered r = t*512 + b

// ---- workspace layout (bytes, all 256-aligned) ----
constexpr size_t OFF_A    = 0;                                   // bf16 [M1][KP]
constexpr size_t SZ_A     = (size_t)M1_C * KP_C * 2;
constexpr size_t OFF_W1T  = OFF_A + SZ_A;                        // bf16 [2048][KP]
constexpr size_t SZ_W1T   = (size_t)G4_C * KP_C * 2;
constexpr size_t OFF_U1T  = OFF_W1T + SZ_W1T;                    // bf16 [2048][512]
constexpr size_t SZ_U1T   = (size_t)G4_C * H_C * 2;
constexpr size_t OFF_XW1  = OFF_U1T + SZ_U1T;                    // fp16 [M1][2048]
constexpr size_t SZ_XW1   = (size_t)M1_C * G4_C * 2;
constexpr size_t OFF_H    = OFF_XW1 + SZ_XW1;                    // bf16 [2][512][512]
constexpr size_t SZ_H     = (size_t)2 * B_C * H_C * 2;
constexpr size_t OFF_XMID = OFF_H + SZ_H;                        // f32 [M1][512]
constexpr size_t SZ_XMID  = (size_t)M1_C * H_C * 4;
constexpr size_t OFF_XW2  = OFF_XMID + SZ_XMID;                  // f32 [M1][20]
constexpr size_t SZ_XW2   = (size_t)M1_C * 20 * 4;
constexpr size_t OFF_W2T  = OFF_XW2 + SZ_XW2;                    // f32 [20][512]
constexpr size_t SZ_W2T   = (size_t)20 * H_C * 4;
constexpr size_t OFF_CNT  = OFF_W2T + SZ_W2T;                    // u32 flags, one per 64B line

// ---- helpers ----
DEVINL unsigned short f2bf(float f) {
  unsigned u = __builtin_bit_cast(unsigned, f);
  u += 0x7fffu + ((u >> 16) & 1u);          // RNE
  return (unsigned short)(u >> 16);
}
DEVINL float sigm(float x) {
  return __builtin_amdgcn_rcpf(1.f + __builtin_amdgcn_exp2f(-1.4426950408889634f * x));
}
DEVINL float tanh_(float x) {
  return 2.f * __builtin_amdgcn_rcpf(1.f + __builtin_amdgcn_exp2f(-2.8853900817779268f * x)) - 1.f;
}
DEVINL void gl_lds16(const void* g, void* l) {
  __builtin_amdgcn_global_load_lds((const __attribute__((address_space(1))) void*)g,
                                   (__attribute__((address_space(3))) void*)l, 16, 0, 0);
}
DEVINL void gl_lds16_coh(const void* g, void* l) {   // SC0|SC1: bypass non-coherent L2, read at IC
  __builtin_amdgcn_global_load_lds((const __attribute__((address_space(1))) void*)g,
                                   (__attribute__((address_space(3))) void*)l, 16, 0, 17);
}

// ================= pack kernels =================

__global__ void pack_a(const float* __restrict__ img, const float* __restrict__ lbl,
                       unsigned short* __restrict__ A) {
  int gid = blockIdx.x * blockDim.x + threadIdx.x;
  constexpr int CPR = KP_C / 8;                       // 100 chunks per row
  if (gid >= M1_C * CPR) return;
  int r  = gid / CPR;
  int cc = gid - r * CPR;
  int t = r >> 9, b = r & 511;
  int k1 = t / 5, n = t - k1 * 5;
  int c0 = cc * 8;
  ushort8 v;
  if (c0 + 8 <= DIMS_C) {
    const float* p = img + ((size_t)((b * 11 + k1) * 5 + n)) * DIMS_C + c0;
    f32x4 x0 = *(const f32x4*)(p);
    f32x4 x1 = *(const f32x4*)(p + 4);
#pragma unroll
    for (int j = 0; j < 4; ++j) { v[j] = f2bf(x0[j]); v[4 + j] = f2bf(x1[j]); }
  } else {
#pragma unroll
    for (int j = 0; j < 8; ++j) {
      int c = c0 + j;
      float x = 0.f;
      if (c < DIMS_C) x = img[((size_t)((b * 11 + k1) * 5 + n)) * DIMS_C + c];
      else if (c < I0_C && k1 < 10) x = lbl[((size_t)((b * 11 + k1) * 5 + n)) * 5 + (c - DIMS_C)];
      v[j] = f2bf(x);
    }
  }
  *(ushort8*)(A + (size_t)r * KP_C + c0) = v;
}

__global__ void pack_w1t(const float* __restrict__ W1, unsigned short* __restrict__ W1T) {
  int gid = blockIdx.x * blockDim.x + threadIdx.x;
  if (gid >= G4_C * KP_C) return;
  int col = gid / KP_C, k = gid - col * KP_C;
  float x = (k < I0_C) ? W1[(size_t)k * G4_C + col] : 0.f;
  W1T[(size_t)col * KP_C + k] = f2bf(x);
}

__global__ void pack_u1t(const float* __restrict__ U1, unsigned short* __restrict__ U1T) {
  int gid = blockIdx.x * blockDim.x + threadIdx.x;
  if (gid >= G4_C * H_C) return;
  int col = gid / H_C, k = gid - col * H_C;
  U1T[(size_t)col * H_C + k] = f2bf(U1[(size_t)k * G4_C + col]);
}

__global__ void pack_w2t(const float* __restrict__ W2, float* __restrict__ W2T) {
  int gid = blockIdx.x * blockDim.x + threadIdx.x;
  if (gid >= 20 * H_C) return;
  int col = gid / H_C, k = gid - col * H_C;
  W2T[(size_t)col * H_C + k] = W2[(size_t)k * 20 + col];
}

// ================= gemm1: xw1 = A @ W1 + b1  (bf16 MFMA, 2-phase + XCD swizzle) =====
__launch_bounds__(256, 2)
__global__ void gemm1(const unsigned short* __restrict__ A,
                      const unsigned short* __restrict__ Bt,
                      const float* __restrict__ bias,
                      _Float16* __restrict__ C)
{
  __shared__ unsigned short sA[2][128 * 32];
  __shared__ unsigned short sB[2][128 * 32];
  const int tid = threadIdx.x;
  const int w = tid >> 6, l = tid & 63;
  const int lo = l & 15, hi = l >> 4;
  const int wm = w >> 1, wn = w & 1;
  const int id = blockIdx.x;
  const int swz = (id & 7) * 440 + (id >> 3);   // XCD chunked, bijective (3520 % 8 == 0)
  const int by = swz >> 4;                      // 0..219  (M tiles)
  const int bx = swz & 15;                      // 0..15   (N tiles)

  const unsigned short* aSrc[2];
  const unsigned short* bSrc[2];
#pragma unroll
  for (int q = 0; q < 2; ++q) {
    int row = w * 32 + q * 16 + (l >> 2);
    int ch = l & 3;
    int sw = (row >> 1) & 3;
    aSrc[q] = A  + (size_t)(by * 128 + row) * KP_C + (ch ^ sw) * 8;
    bSrc[q] = Bt + (size_t)(bx * 128 + row) * KP_C + (ch ^ sw) * 8;
  }
  int aOff[4], bOff[4];
#pragma unroll
  for (int i = 0; i < 4; ++i) {
    int rA = wm * 64 + i * 16 + lo;
    aOff[i] = rA * 32 + ((hi ^ ((rA >> 1) & 3)) * 8);
    int rB = wn * 64 + i * 16 + lo;
    bOff[i] = rB * 32 + ((hi ^ ((rB >> 1) & 3)) * 8);
  }

  f32x4 acc[4][4];
#pragma unroll
  for (int i = 0; i < 4; ++i)
#pragma unroll
    for (int j = 0; j < 4; ++j) acc[i][j] = (f32x4){0.f, 0.f, 0.f, 0.f};

#define G1_STAGE(buf, ks)                                                  \
  {                                                                        \
    _Pragma("unroll")                                                      \
    for (int q = 0; q < 2; ++q) {                                          \
      gl_lds16(aSrc[q] + (ks) * 32, &sA[buf][w * 1024 + q * 512]);         \
      gl_lds16(bSrc[q] + (ks) * 32, &sB[buf][w * 1024 + q * 512]);         \
    }                                                                      \
  }

  G1_STAGE(0, 0);
  asm volatile("s_waitcnt vmcnt(0)" ::: "memory");
  __syncthreads();

  int cur = 0;
#pragma unroll 1
  for (int ks = 0; ks < KP_C / 32; ++ks) {
    if (ks < KP_C / 32 - 1) G1_STAGE(cur ^ 1, ks + 1);
    bf16x8 af[4], bfr[4];
#pragma unroll
    for (int i = 0; i < 4; ++i) {
      af[i]  = *(const bf16x8*)(&sA[cur][0] + aOff[i]);
      bfr[i] = *(const bf16x8*)(&sB[cur][0] + bOff[i]);
    }
#pragma unroll
    for (int mi = 0; mi < 4; ++mi)
#pragma unroll
      for (int ni = 0; ni < 4; ++ni)
        acc[mi][ni] = __builtin_amdgcn_mfma_f32_16x16x32_bf16(af[mi], bfr[ni], acc[mi][ni], 0, 0, 0);
    asm volatile("s_waitcnt vmcnt(0)" ::: "memory");
    __syncthreads();
    cur ^= 1;
  }
#undef G1_STAGE

  const size_t crow0 = (size_t)by * 128 + wm * 64;
  const int ccol0 = bx * 128 + wn * 64;
#pragma unroll
  for (int ni = 0; ni < 4; ++ni) {
    int col = ccol0 + ni * 16 + lo;
    float bv = bias[col];
#pragma unroll
    for (int mi = 0; mi < 4; ++mi) {
#pragma unroll
      for (int j = 0; j < 4; ++j) {
        size_t row = crow0 + mi * 16 + hi * 4 + j;
        C[row * G4_C + col] = (_Float16)(acc[mi][ni][j] + bv);
      }
    }
  }
}

// ================= lstm1: persistent recurrence, 512 blocks / 2 per CU ============
// 512 blocks = 32 batch-groups (16 rows) x 16 unit-groups (32 units), 2 blocks/CU.
// Co-resident blocks are from independent sync domains -> one computes while the
// other polls/drains (latency hiding via TLP, not chain tuning). Per block: wave g
// owns gate g (bu[2][16] = 128 VGPR); r6-proven protocol: sG exchange, coalesced
// h-stores, signal BEFORE xmid/xw prefetch so they overlap the poll.
__launch_bounds__(256, 2)
__global__ void lstm1(const _Float16* __restrict__ xw,        // [M1][2048]
                      const unsigned short* __restrict__ U1T, // [2048 cols][512 k] bf16
                      unsigned short* __restrict__ hbuf,      // [2][512][512] bf16
                      float* __restrict__ xmid,               // [M1][512]
                      unsigned int* __restrict__ cnt)         // flag (bg,cg) at [(bg*16+cg)*16]
{
  __shared__ unsigned short sH[16 * 512];   // 16 KB; [row][chunk c] = global chunk c^(row&7)
  __shared__ float sG[4 * 16 * 32];         // 8 KB gate exchange

  const int tid = threadIdx.x;
  const int g = tid >> 6;                   // wave = gate
  const int l = tid & 63;
  const int lo = l & 15, hi = l >> 4;
  const int bg = blockIdx.x >> 4;           // 0..31
  const int cg = blockIdx.x & 15;
  const int brow0 = bg * 16;
  const int ub = cg * 32;

  // U1 B-fragments for this gate: bu[nf][kk], unit = ub+nf*16+lo, k = kk*32+hi*8+i
  bf16x8 bu[2][16];
#pragma unroll
  for (int nf = 0; nf < 2; ++nf) {
    const unsigned short* src = U1T + ((size_t)(g * H_C + ub + nf * 16 + lo)) * H_C + hi * 8;
#pragma unroll
    for (int kk = 0; kk < 16; ++kk)
      bu[nf][kk] = *(const bf16x8*)(src + kk * 32);
  }

  // A-frag addressing: row = lo (16 rows), stage pre-swizzled by row&7
  const int s0 = lo & 7;
  const int aO0 = lo * 1024;

  // cell ownership: rows rbase..rbase+1, unit u
  const int half = l >> 5;
  const int u = l & 31;
  const int rbase = g * 4 + half * 2;
  const int uread = u ^ (g << 3);           // row>>2 == g for owned rows

  float c_st[2] = {0.f, 0.f};

  // xw for t=0
  const _Float16* xb = xw + (size_t)(brow0 + rbase) * G4_C + ub + u;
  float xwv[4][2];
#pragma unroll
  for (int g2 = 0; g2 < 4; ++g2)
#pragma unroll
    for (int j = 0; j < 2; ++j)
      xwv[g2][j] = (float)xb[(size_t)j * G4_C + g2 * H_C];

#pragma unroll 1
  for (int t = 0; t < T_C; ++t) {
    f32x4 acc[2];
    acc[0] = (f32x4){0.f, 0.f, 0.f, 0.f};
    acc[1] = (f32x4){0.f, 0.f, 0.f, 0.f};

    if (t > 0) {
      // ---- per-wave poll: 16 flags, each in its own 64B line
      {
        const unsigned* fp = cnt + (size_t)(bg * 16 + (l & 15)) * 16;
        unsigned target = (unsigned)t;
        while (true) {
          unsigned v = __hip_atomic_load(fp, RLX, AGT);
          if (__all(v >= target)) break;
          __builtin_amdgcn_s_sleep(1);
        }
      }
      asm volatile("" ::: "memory");   // keep gl_lds below the poll

      // ---- stage h(t): wave g stages rows g*4..g*4+3, source pre-swizzled (l^(row&7))
      const unsigned short* hsrc = hbuf + (size_t)(t & 1) * (B_C * H_C);
#pragma unroll
      for (int p = 0; p < 4; ++p) {
        int row = g * 4 + p;
        gl_lds16_coh(hsrc + (size_t)(brow0 + row) * H_C + ((l ^ (row & 7)) * 8),
                     sH + row * 512);
      }
      asm volatile("s_waitcnt vmcnt(0)" ::: "memory");
      __syncthreads();

      // ---- z(gate g) = h @ U1 : M=16 x N=32 x K=512
#pragma unroll
      for (int kk = 0; kk < 16; ++kk) {
        int off = (((kk * 4 + hi) ^ s0) << 4);
        bf16x8 a0 = *(const bf16x8*)((const char*)sH + aO0 + off);
        acc[0] = __builtin_amdgcn_mfma_f32_16x16x32_bf16(a0, bu[0][kk], acc[0], 0, 0, 0);
        acc[1] = __builtin_amdgcn_mfma_f32_16x16x32_bf16(a0, bu[1][kk], acc[1], 0, 0, 0);
      }
    }

    // ---- write this gate's z tile to sG (swizzled unit index)
#pragma unroll
    for (int nf = 0; nf < 2; ++nf)
#pragma unroll
      for (int j = 0; j < 4; ++j) {
        int row = hi * 4 + j;
        sG[g * 512 + row * 32 + ((nf * 16 + lo) ^ (hi << 3))] = acc[nf][j];
      }
    __syncthreads();

    // ---- gather 4 gates, activate, update state (2 cells/thread)
    float hnew[2];
#pragma unroll
    for (int j = 0; j < 2; ++j) {
      int r = rbase + j;
      float zi = sG[0 * 512 + r * 32 + uread] + xwv[0][j];
      float zf = sG[1 * 512 + r * 32 + uread] + xwv[1][j];
      float zg = sG[2 * 512 + r * 32 + uread] + xwv[2][j];
      float zo = sG[3 * 512 + r * 32 + uread] + xwv[3][j];
      float iv = sigm(zi), fv = sigm(zf), gv = tanh_(zg), ov = sigm(zo);
      float cv = fv * c_st[j] + iv * gv;
      c_st[j] = cv;
      hnew[j] = ov * tanh_(cv);
    }

    if (t < T_C - 1) {
      // ---- h(t+1) coherent packed-u32 stores (wide: 32 lanes/wave active)
      unsigned short* hd = hbuf + (size_t)((t & 1) ^ 1) * (B_C * H_C);
#pragma unroll
      for (int j = 0; j < 2; ++j) {
        float other = __shfl_xor(hnew[j], 1);
        if ((u & 1) == 0) {
          unsigned val = (unsigned)f2bf(hnew[j]) | ((unsigned)f2bf(other) << 16);
          __hip_atomic_store((unsigned*)(hd + (size_t)(brow0 + rbase + j) * H_C + ub + u), val,
                             RLX, AGT);
        }
      }

      // drains every thread's h stores (vmcnt ack = IC visibility), then signal
      __syncthreads();
      if (tid == 0)
        __hip_atomic_store(&cnt[(size_t)(bg * 16 + cg) * 16], (unsigned)(t + 1), RLX, AGT);

      // ---- off-critical-path: xmid (NT) + xw(t+1) prefetch overlap the next poll
#pragma unroll
      for (int j = 0; j < 2; ++j)
        __builtin_nontemporal_store(hnew[j],
            &xmid[((size_t)t * B_C + brow0 + rbase + j) * H_C + ub + u]);
      const _Float16* xp = xb + (size_t)(t + 1) * B_C * G4_C;
#pragma unroll
      for (int g2 = 0; g2 < 4; ++g2)
#pragma unroll
        for (int j = 0; j < 2; ++j)
          xwv[g2][j] = (float)xp[(size_t)j * G4_C + g2 * H_C];
    } else {
#pragma unroll
      for (int j = 0; j < 2; ++j)
        __builtin_nontemporal_store(hnew[j],
            &xmid[((size_t)t * B_C + brow0 + rbase + j) * H_C + ub + u]);
    }
  }
}

// ================= gemm2: xw2 = x_mid @ W2 + b2 (fp32, 1 thread/row) =================
__global__ void gemm2(const float* __restrict__ X,    // [M1][512]
                      const float* __restrict__ W2T,  // [20][512]
                      const float* __restrict__ b2,   // [20]
                      float* __restrict__ XW2)        // [M1][20]
{
  int r = blockIdx.x * blockDim.x + threadIdx.x;
  if (r >= M1_C) return;
  float acc[20];
#pragma unroll
  for (int j = 0; j < 20; ++j) acc[j] = b2[j];
  const float* xr = X + (size_t)r * H_C;
  for (int k = 0; k < H_C; k += 4) {
    f32x4 xv = *(const f32x4*)(xr + k);
#pragma unroll
    for (int j = 0; j < 20; ++j) {
      f32x4 wv = *(const f32x4*)(W2T + (size_t)j * H_C + k);
      acc[j] += xv[0]*wv[0] + xv[1]*wv[1] + xv[2]*wv[2] + xv[3]*wv[3];
    }
  }
  float* op = XW2 + (size_t)r * 20;
#pragma unroll
  for (int j = 0; j < 20; ++j) op[j] = acc[j];
}

// ================= lstm2: tiny recurrence, fp32 =================
__global__ void lstm2(const float* __restrict__ XW2,  // [M1][20]
                      const float* __restrict__ U2,   // [5][20]
                      float* __restrict__ out)        // [512][11][5][5]
{
  int b = blockIdx.x * blockDim.x + threadIdx.x;
  if (b >= B_C) return;
  float u2[5][20];
#pragma unroll
  for (int k = 0; k < 5; ++k)
#pragma unroll
    for (int j = 0; j < 20; ++j) u2[k][j] = U2[k * 20 + j];
  float h[5] = {0, 0, 0, 0, 0}, c[5] = {0, 0, 0, 0, 0};
  for (int t = 0; t < T_C; ++t) {
    const float* xr = XW2 + ((size_t)t * B_C + b) * 20;
    float z[20];
#pragma unroll
    for (int j = 0; j < 20; ++j) z[j] = xr[j];
#pragma unroll
    for (int k = 0; k < 5; ++k) {
      float hk = h[k];
#pragma unroll
      for (int j = 0; j < 20; ++j) z[j] += hk * u2[k][j];
    }
#pragma unroll
    for (int n = 0; n < 5; ++n) {
      float iv = sigm(z[n]), fv = sigm(z[5 + n]), gv = tanh_(z[10 + n]), ov = sigm(z[15 + n]);
      c[n] = fv * c[n] + iv * gv;
      h[n] = ov * tanh_(c[n]);
    }
    int k1 = t / 5, nn = t - k1 * 5;
    float* op = out + (((size_t)b * 11 + k1) * 5 + nn) * 5;
#pragma unroll
    for (int j = 0; j < 5; ++j) op[j] = h[j];
  }
}

// ================= launch =================
extern "C" void kernel_launch(void* const* d_in, const int* in_sizes, int n_in,
                              void* d_out, int out_size, void* d_ws, size_t ws_size,
                              hipStream_t stream) {
  (void)in_sizes; (void)n_in; (void)out_size; (void)ws_size;
  const float* img = (const float*)d_in[0];
  const float* lbl = (const float*)d_in[1];
  const float* W1  = (const float*)d_in[2];
  const float* U1  = (const float*)d_in[3];
  const float* b1  = (const float*)d_in[4];
  const float* W2  = (const float*)d_in[5];
  const float* U2  = (const float*)d_in[6];
  const float* b2  = (const float*)d_in[7];

  char* ws = (char*)d_ws;
  unsigned short* A    = (unsigned short*)(ws + OFF_A);
  unsigned short* W1T  = (unsigned short*)(ws + OFF_W1T);
  unsigned short* U1T  = (unsigned short*)(ws + OFF_U1T);
  _Float16*       XW1  = (_Float16*)      (ws + OFF_XW1);
  unsigned short* HB   = (unsigned short*)(ws + OFF_H);
  float*          XMID = (float*)         (ws + OFF_XMID);
  float*          XW2  = (float*)         (ws + OFF_XW2);
  float*          W2T  = (float*)         (ws + OFF_W2T);
  unsigned int*   CNT  = (unsigned int*)  (ws + OFF_CNT);

  hipMemsetAsync(CNT, 0, 512 * 64, stream);               // 512 flags, one per 64B line

  pack_a  <<<(M1_C * (KP_C / 8)) / 256, 256, 0, stream>>>(img, lbl, A);
  pack_w1t<<<(G4_C * KP_C) / 256,      256, 0, stream>>>(W1, W1T);
  pack_u1t<<<(G4_C * H_C) / 256,       256, 0, stream>>>(U1, U1T);
  pack_w2t<<<(20 * H_C + 255) / 256,   256, 0, stream>>>(W2, W2T);

  gemm1<<<3520, 256, 0, stream>>>(A, W1T, b1, XW1);
  lstm1<<<512, 256, 0, stream>>>(XW1, U1T, HB, XMID, CNT);
  gemm2<<<(M1_C + 255) / 256, 256, 0, stream>>>(XMID, W2T, b2, XW2);
  lstm2<<<8, 64, 0, stream>>>(XW2, U2, (float*)d_out);
}